// Round 10
// baseline (1688.368 us; speedup 1.0000x reference)
//
#include <hip/hip_runtime.h>

#define N_NODES 100000
#define N_EDGES 3200000
#define N_GRAPHS 5000
#define BN_EPS 1e-5f
#define HPAD 80        // hidden 75 padded to 80
#define CHUNK 4096     // edges per bucket-sort block
#define NBLKA 782      // ceil(N_EDGES / CHUNK)
#define NBKT 1564      // buckets of 64 nodes (dst >> 6); bucket 1563 always empty
#define NBKT_USED 1563 // buckets that contain real nodes
#define NS1 4778       // ceil(NBKT*NBLKA / 256)
#define LALLOC (NS1 * 256)   // 1223168 >= NBKT*NBLKA = 1223048
#define VPT 19         // ceil(NS1 / 256) for ks2

// ---------- node encoder: h = x @ node_w + node_b ----------
__global__ void k_encode(const float* __restrict__ x, const float* __restrict__ W,
                         const float* __restrict__ b, float* __restrict__ h) {
    __shared__ float sW[448];
    __shared__ float sb[32];
    for (int i = threadIdx.x; i < 448; i += 256) sW[i] = W[i];
    if (threadIdx.x < 32) sb[threadIdx.x] = b[threadIdx.x];
    __syncthreads();
    int n = blockIdx.x * 256 + threadIdx.x;
    if (n >= N_NODES) return;
    float xi[14];
#pragma unroll
    for (int k = 0; k < 14; k++) xi[k] = x[n * 14 + k];
    float4* hp = (float4*)(h + (size_t)n * 32);
#pragma unroll
    for (int q = 0; q < 8; q++) {
        float4 acc;
        float* ap = (float*)&acc;
#pragma unroll
        for (int i = 0; i < 4; i++) {
            int c = q * 4 + i;
            float a = sb[c];
#pragma unroll
            for (int k = 0; k < 14; k++) a += xi[k] * sW[k * 32 + c];
            ap[i] = a;
        }
        hp[q] = acc;
    }
}

// ---------- weight prep ----------
__global__ void k_prep(const float* __restrict__ W1, const float* __restrict__ b1,
                       const float* __restrict__ W2,
                       float* __restrict__ w1tp, float* __restrict__ b1p,
                       float* __restrict__ w2p) {
    int i = blockIdx.x * 256 + threadIdx.x;
    if (i < 2 * HPAD * 32) {
        int l = i / (HPAD * 32), r = i % (HPAD * 32);
        int j = r / 32, c = r % 32;
        w1tp[i] = (j < 75) ? W1[l * 2400 + c * 75 + j] : 0.f;
        w2p[i]  = (j < 75) ? W2[l * 2400 + j * 32 + c] : 0.f;
    } else if (i < 2 * HPAD * 32 + 2 * HPAD) {
        int k = i - 2 * HPAD * 32;
        int l = k / HPAD, j = k % HPAD;
        b1p[k] = (j < 75) ? b1[l * 75 + j] : 0.f;
    }
}

// ---------- bucket sort phase A: per-block bucket histogram ----------
__global__ void __launch_bounds__(256) ksA(const int* __restrict__ ei, int* __restrict__ cmat) {
    __shared__ int lh[NBKT];
    for (int i = threadIdx.x; i < NBKT; i += 256) lh[i] = 0;
    __syncthreads();
    int b0 = blockIdx.x * CHUNK;
    for (int i = threadIdx.x; i < CHUNK; i += 256) {
        int e = b0 + i;
        if (e < N_EDGES) atomicAdd(&lh[ei[N_EDGES + e] >> 6], 1);
    }
    __syncthreads();
    for (int b = threadIdx.x; b < NBKT; b += 256) cmat[b * NBLKA + blockIdx.x] = lh[b];
}

// ---------- parallel exclusive scan of cmat (bucket-major logical order) ----------
__global__ void ks1(const int* __restrict__ a, int* __restrict__ bs) {
    __shared__ int s[256];
    int i = blockIdx.x * 256 + threadIdx.x;
    s[threadIdx.x] = a[i];
    __syncthreads();
    for (int o = 128; o > 0; o >>= 1) {
        if (threadIdx.x < o) s[threadIdx.x] += s[threadIdx.x + o];
        __syncthreads();
    }
    if (threadIdx.x == 0) bs[blockIdx.x] = s[0];
}

__global__ void ks2(int* __restrict__ bs) {   // single block scans NS1 block-sums
    __shared__ int s[256];
    int t = threadIdx.x;
    int v[VPT];
    int base = t * VPT, sum = 0;
#pragma unroll
    for (int k = 0; k < VPT; k++) {
        int idx = base + k;
        int x = (idx < NS1) ? bs[idx] : 0;
        v[k] = sum; sum += x;
    }
    s[t] = sum;
    __syncthreads();
    for (int o = 1; o < 256; o <<= 1) {
        int add = (t >= o) ? s[t - o] : 0;
        __syncthreads();
        s[t] += add;
        __syncthreads();
    }
    int excl = (t == 0) ? 0 : s[t - 1];
#pragma unroll
    for (int k = 0; k < VPT; k++) {
        int idx = base + k;
        if (idx < NS1) bs[idx] = excl + v[k];
    }
}

__global__ void ks3(int* __restrict__ a, const int* __restrict__ bs) {
    __shared__ int s[256];
    int t = threadIdx.x, i = blockIdx.x * 256 + t;
    int v = a[i];
    s[t] = v;
    __syncthreads();
    for (int o = 1; o < 256; o <<= 1) {
        int add = (t >= o) ? s[t - o] : 0;
        __syncthreads();
        s[t] += add;
        __syncthreads();
    }
    a[i] = s[t] - v + bs[blockIdx.x];
}

// ---------- phase B: scatter records into bucket-grouped buf1 (LDS cursors) ----------
__global__ void __launch_bounds__(256) ksB(const int* __restrict__ ei, const float* __restrict__ ea,
                                           const int* __restrict__ cmat, float4* __restrict__ buf1) {
    __shared__ int base[NBKT];
    for (int i = threadIdx.x; i < NBKT; i += 256) base[i] = cmat[i * NBLKA + blockIdx.x];
    __syncthreads();
    int b0 = blockIdx.x * CHUNK;
    for (int i = threadIdx.x; i < CHUNK; i += 256) {
        int e = b0 + i;
        if (e >= N_EDGES) break;
        int src = ei[e], dst = ei[N_EDGES + e];
        float a0 = ea[(size_t)e * 3 + 0], a1 = ea[(size_t)e * 3 + 1], a2 = ea[(size_t)e * 3 + 2];
        int pos = atomicAdd(&base[dst >> 6], 1);
        buf1[pos] = make_float4(a0, a1, a2, __int_as_float(src | ((dst & 63) << 17)));
    }
}

// ---------- pull aggregation over bucket-grouped edges, LDS accumulators ----------
// One block per 64-node bucket. acc rows padded to 33 floats: bank = (dl + c) % 32,
// distinct dl -> distinct banks. 8 threads per edge (quad q = t&7), edge weights in regs.
__global__ void __launch_bounds__(256) k_agg(const float4* __restrict__ buf1,
                                             const int* __restrict__ cmat,
                                             const float* __restrict__ eW, const float* __restrict__ eb,
                                             const float* __restrict__ h, float* __restrict__ agg) {
    __shared__ float acc[64 * 33];
    int g = blockIdx.x, t = threadIdx.x;
    for (int i = t; i < 64 * 33; i += 256) acc[i] = 0.f;
    int q = t & 7, grp = t >> 3;          // 32 edge-groups of 8 lanes
    int c0 = q * 4;
    float w0[4], w1[4], w2[4], bb4[4];
#pragma unroll
    for (int i = 0; i < 4; i++) {
        w0[i] = eW[c0 + i];
        w1[i] = eW[32 + c0 + i];
        w2[i] = eW[64 + c0 + i];
        bb4[i] = eb[c0 + i];
    }
    int bb = cmat[g * NBLKA];
    int be = cmat[(g + 1) * NBLKA];       // g <= 1562 < NBKT-1, always valid
    __syncthreads();
    for (int e = bb + grp; e < be; e += 32) {
        float4 p = buf1[e];               // 8 lanes same address -> broadcast
        int bits = __float_as_int(p.w);
        int src = bits & 0x1FFFF, dl = bits >> 17;
        float4 hs = *(const float4*)(h + (size_t)src * 32 + c0);
        const float* hp = (const float*)&hs;
        float* arow = &acc[dl * 33 + c0];
#pragma unroll
        for (int i = 0; i < 4; i++) {
            float m = hp[i] + p.x * w0[i] + p.y * w1[i] + p.z * w2[i] + bb4[i];
            atomicAdd(&arow[i], fmaxf(m, 0.f));
        }
    }
    __syncthreads();
    for (int idx = t; idx < 2048; idx += 256) {
        int n = g * 64 + (idx >> 5);
        if (n < N_NODES) agg[(size_t)n * 32 + (idx & 31)] = acc[(idx >> 5) * 33 + (idx & 31)];
    }
}

// ---------- fused MLP: z = relu((h+agg)@W1+b1)@W2+b2, written over agg ----------
__global__ void __launch_bounds__(256, 4) k_mlp(const float* __restrict__ h, float* __restrict__ agg,
                                                const float* __restrict__ W1, const float* __restrict__ B1,
                                                const float* __restrict__ W2, const float* __restrict__ b2) {
    unsigned t = blockIdx.x * 256 + threadIdx.x;   // N_NODES*8 exact
    unsigned lane = threadIdx.x & 63;
    unsigned oct = lane >> 3;          // hidden-slice / output-quad index
    unsigned nd = lane & 7;            // node within this wave's 8-node group
    unsigned n = (t >> 6) * 8 + nd;    // 12500 waves * 8 nodes = N_NODES exact
    const float4* hp = (const float4*)(h + (size_t)n * 32);
    const float4* ap = (const float4*)(agg + (size_t)n * 32);
    float zc[32];
#pragma unroll
    for (int q = 0; q < 8; q++) {
        float4 hv = hp[q], av = ap[q];
        zc[q * 4 + 0] = hv.x + av.x;
        zc[q * 4 + 1] = hv.y + av.y;
        zc[q * 4 + 2] = hv.z + av.z;
        zc[q * 4 + 3] = hv.w + av.w;
    }
    float hid[10];
#pragma unroll
    for (int i = 0; i < 10; i++) {
        int j = (int)oct * 10 + i;
        const float4* wp = (const float4*)(W1 + j * 32);
        float a0 = 0.f, a1 = 0.f, a2 = 0.f, a3 = 0.f;
#pragma unroll
        for (int q = 0; q < 8; q++) {
            float4 wv = wp[q];
            a0 += zc[q * 4 + 0] * wv.x;
            a1 += zc[q * 4 + 1] * wv.y;
            a2 += zc[q * 4 + 2] * wv.z;
            a3 += zc[q * 4 + 3] * wv.w;
        }
        hid[i] = fmaxf(B1[j] + ((a0 + a1) + (a2 + a3)), 0.f);
    }
    float4 zo = *(const float4*)(b2 + oct * 4);
#pragma unroll
    for (int p = 0; p < 8; p++) {
        int srcl = (int)nd | (p << 3);
#pragma unroll
        for (int i = 0; i < 10; i++) {
            float hj = __shfl(hid[i], srcl, 64);
            float4 wv = *(const float4*)(W2 + (p * 10 + i) * 32 + oct * 4);
            zo.x += hj * wv.x;
            zo.y += hj * wv.y;
            zo.z += hj * wv.z;
            zo.w += hj * wv.w;
        }
    }
    *(float4*)(agg + (size_t)n * 32 + oct * 4) = zo;
}

// ---------- BN stats ----------
__global__ void __launch_bounds__(256) k_stats(const float* __restrict__ z, float* __restrict__ stats) {
    __shared__ float ls[4 * 64];
    int tid = threadIdx.x;
    int c = tid & 31;
    float s = 0.f, s2 = 0.f;
    for (int e = blockIdx.x * 256 + tid; e < N_NODES * 32; e += 256 * 256) {
        float v = z[e];
        s += v; s2 += v * v;
    }
    s += __shfl_down(s, 32, 64);
    s2 += __shfl_down(s2, 32, 64);
    int wave = tid >> 6, lane = tid & 63;
    if (lane < 32) { ls[wave * 64 + c] = s; ls[wave * 64 + 32 + c] = s2; }
    __syncthreads();
    if (tid < 64) {
        float a = ls[tid] + ls[64 + tid] + ls[128 + tid] + ls[192 + tid];
        atomicAdd(&stats[tid], a);
    }
}

// ---------- BN apply + relu ----------
__global__ void k_bn(const float* __restrict__ z, float* __restrict__ h,
                     const float* __restrict__ stats, const float* __restrict__ g,
                     const float* __restrict__ b) {
    int t = blockIdx.x * 256 + threadIdx.x;
    if (t >= N_NODES * 8) return;
    int q = t & 7;
    float4 zv = ((const float4*)z)[t];
    float* zp = (float*)&zv;
    float4 ov;
    float* op = (float*)&ov;
    const float invN = 1.0f / (float)N_NODES;
#pragma unroll
    for (int i = 0; i < 4; i++) {
        int c = q * 4 + i;
        float mu = stats[c] * invN;
        float var = stats[32 + c] * invN - mu * mu;
        float sc = g[c] / sqrtf(var + BN_EPS);
        op[i] = fmaxf((zp[i] - mu) * sc + b[c], 0.f);
    }
    ((float4*)h)[t] = ov;
}

// ---------- graph offsets (batch is sorted) ----------
__global__ void k_goff(const int* __restrict__ batch, int* __restrict__ goff) {
    int g = blockIdx.x * 256 + threadIdx.x;
    if (g > N_GRAPHS) return;
    int lo = 0, hi = N_NODES;
    while (lo < hi) {
        int mid = (lo + hi) >> 1;
        if (batch[mid] < g) lo = mid + 1; else hi = mid;
    }
    goff[g] = lo;
}

// ---------- mean-pool: one wave per graph ----------
__global__ void __launch_bounds__(256) k_pool2(const float* __restrict__ h, const int* __restrict__ goff,
                                               float* __restrict__ gsum) {
    int wid = threadIdx.x >> 6, lane = threadIdx.x & 63;
    int g = blockIdx.x * 4 + wid;
    if (g >= N_GRAPHS) return;
    int s = goff[g], e = goff[g + 1];
    int c = lane & 31, half = lane >> 5;
    float acc = 0.f;
    for (int n = s + half; n < e; n += 2) acc += h[(size_t)n * 32 + c];
    acc += __shfl_down(acc, 32, 64);
    if (lane < 32) gsum[(size_t)g * 32 + c] = acc;
}

__global__ void k_head(const float* __restrict__ gsum, const int* __restrict__ goff,
                       const float* __restrict__ W1, const float* __restrict__ b1,
                       const float* __restrict__ W2, const float* __restrict__ b2,
                       float* __restrict__ out) {
    __shared__ float sW1[512], sb1[16], sW2[32], sb2[2];
    for (int i = threadIdx.x; i < 512; i += 256) sW1[i] = W1[i];
    if (threadIdx.x < 16) sb1[threadIdx.x] = b1[threadIdx.x];
    if (threadIdx.x < 32) sW2[threadIdx.x] = W2[threadIdx.x];
    if (threadIdx.x < 2) sb2[threadIdx.x] = b2[threadIdx.x];
    __syncthreads();
    int gI = blockIdx.x * 256 + threadIdx.x;
    if (gI >= N_GRAPHS) return;
    float cnt = (float)(goff[gI + 1] - goff[gI]);
    float inv = 1.0f / fmaxf(cnt, 1.0f);
    float gx[32];
#pragma unroll
    for (int c = 0; c < 32; c++) gx[c] = gsum[(size_t)gI * 32 + c] * inv;
    float hid[16];
#pragma unroll
    for (int j = 0; j < 16; j++) {
        float a = sb1[j];
#pragma unroll
        for (int c = 0; c < 32; c++) a += gx[c] * sW1[c * 16 + j];
        hid[j] = fmaxf(a, 0.f);
    }
#pragma unroll
    for (int o = 0; o < 2; o++) {
        float a = sb2[o];
#pragma unroll
        for (int j = 0; j < 16; j++) a += hid[j] * sW2[j * 2 + o];
        out[(size_t)gI * 2 + o] = a;
    }
}

extern "C" void kernel_launch(void* const* d_in, const int* in_sizes, int n_in,
                              void* d_out, int out_size, void* d_ws, size_t ws_size,
                              hipStream_t stream) {
    const float* x       = (const float*)d_in[0];
    const int*   ei      = (const int*)d_in[1];
    const float* eattr   = (const float*)d_in[2];
    const int*   batch   = (const int*)d_in[3];
    const float* node_w  = (const float*)d_in[4];
    const float* node_b  = (const float*)d_in[5];
    const float* edge_w  = (const float*)d_in[6];
    const float* edge_b  = (const float*)d_in[7];
    const float* conv_w1 = (const float*)d_in[8];
    const float* conv_b1 = (const float*)d_in[9];
    const float* conv_w2 = (const float*)d_in[10];
    const float* conv_b2 = (const float*)d_in[11];
    const float* bn_g    = (const float*)d_in[12];
    const float* bn_b    = (const float*)d_in[13];
    const float* lin1_w  = (const float*)d_in[14];
    const float* lin1_b  = (const float*)d_in[15];
    const float* lin2_w  = (const float*)d_in[16];
    const float* lin2_b  = (const float*)d_in[17];
    float* out = (float*)d_out;

    float4* buf1   = (float4*)d_ws;                        // 51.2 MB (persistent edge array)
    float*  h      = (float*)(buf1 + N_EDGES);             // 12.8 MB
    float*  agg    = h + (size_t)N_NODES * 32;             // 12.8 MB (z in-place)
    int*    cmat   = (int*)(agg + (size_t)N_NODES * 32);   // LALLOC ints (~4.9 MB)
    int*    t1     = cmat + LALLOC;                        // 4864
    int*    goff   = t1 + 4864;                            // N_GRAPHS+1
    float*  stats  = (float*)(goff + N_GRAPHS + 1);        // 64
    float*  gsum   = stats + 64;                           // G*32
    float*  w1tp   = gsum + (size_t)N_GRAPHS * 32;         // 2*80*32
    float*  b1p    = w1tp + 2 * HPAD * 32;                 // 2*80
    float*  w2p    = b1p + 2 * HPAD;                       // 2*80*32

    int nb_nodes = (N_NODES + 255) / 256;
    int nb_vec   = (N_NODES * 8 + 255) / 256;

    hipMemsetAsync(cmat, 0, LALLOC * sizeof(int), stream);
    k_encode<<<nb_nodes, 256, 0, stream>>>(x, node_w, node_b, h);
    k_prep<<<(2 * HPAD * 32 + 2 * HPAD + 255) / 256, 256, 0, stream>>>(
        conv_w1, conv_b1, conv_w2, w1tp, b1p, w2p);
    k_goff<<<(N_GRAPHS + 1 + 255) / 256, 256, 0, stream>>>(batch, goff);

    ksA<<<NBLKA, 256, 0, stream>>>(ei, cmat);
    ks1<<<NS1, 256, 0, stream>>>(cmat, t1);
    ks2<<<1, 256, 0, stream>>>(t1);
    ks3<<<NS1, 256, 0, stream>>>(cmat, t1);
    ksB<<<NBLKA, 256, 0, stream>>>(ei, eattr, cmat, buf1);

    for (int l = 0; l < 2; l++) {
        hipMemsetAsync(stats, 0, 64 * sizeof(float), stream);
        k_agg<<<NBKT_USED, 256, 0, stream>>>(buf1, cmat, edge_w, edge_b, h, agg);
        k_mlp<<<N_NODES * 8 / 256, 256, 0, stream>>>(h, agg, w1tp + l * HPAD * 32,
                                                     b1p + l * HPAD, w2p + l * HPAD * 32,
                                                     conv_b2 + l * 32);
        k_stats<<<256, 256, 0, stream>>>(agg, stats);
        k_bn<<<nb_vec, 256, 0, stream>>>(agg, h, stats, bn_g + l * 32, bn_b + l * 32);
    }
    k_pool2<<<(N_GRAPHS + 3) / 4, 256, 0, stream>>>(h, goff, gsum);
    k_head<<<(N_GRAPHS + 255) / 256, 256, 0, stream>>>(gsum, goff, lin1_w, lin1_b, lin2_w, lin2_b, out);
}

// Round 11
// 670.876 us; speedup vs baseline: 2.5167x; 2.5167x over previous
//
#include <hip/hip_runtime.h>

#define N_NODES 100000
#define N_EDGES 3200000
#define N_GRAPHS 5000
#define BN_EPS 1e-5f
#define NPAD 100096    // 1564 * 64
#define HPAD 80        // hidden 75 padded to 80
#define CHUNK 8192     // edges per bucket-sort block
#define NBLKA 391      // ceil(N_EDGES / CHUNK)
#define NBKT 1564      // buckets of 64 nodes (dst >> 6)
#define NS1 2389       // ceil(NBKT*NBLKA / 256)
#define LALLOC (NS1 * 256)   // 611584 >= NBKT*NBLKA = 611524
#define VPT 10         // ceil(NS1 / 256) for ks2

// ---------- node encoder: h = x @ node_w + node_b ----------
__global__ void k_encode(const float* __restrict__ x, const float* __restrict__ W,
                         const float* __restrict__ b, float* __restrict__ h) {
    __shared__ float sW[448];
    __shared__ float sb[32];
    for (int i = threadIdx.x; i < 448; i += 256) sW[i] = W[i];
    if (threadIdx.x < 32) sb[threadIdx.x] = b[threadIdx.x];
    __syncthreads();
    int n = blockIdx.x * 256 + threadIdx.x;
    if (n >= N_NODES) return;
    float xi[14];
#pragma unroll
    for (int k = 0; k < 14; k++) xi[k] = x[n * 14 + k];
    float4* hp = (float4*)(h + (size_t)n * 32);
#pragma unroll
    for (int q = 0; q < 8; q++) {
        float4 acc;
        float* ap = (float*)&acc;
#pragma unroll
        for (int i = 0; i < 4; i++) {
            int c = q * 4 + i;
            float a = sb[c];
#pragma unroll
            for (int k = 0; k < 14; k++) a += xi[k] * sW[k * 32 + c];
            ap[i] = a;
        }
        hp[q] = acc;
    }
}

// ---------- weight prep ----------
__global__ void k_prep(const float* __restrict__ W1, const float* __restrict__ b1,
                       const float* __restrict__ W2,
                       float* __restrict__ w1tp, float* __restrict__ b1p,
                       float* __restrict__ w2p) {
    int i = blockIdx.x * 256 + threadIdx.x;
    if (i < 2 * HPAD * 32) {
        int l = i / (HPAD * 32), r = i % (HPAD * 32);
        int j = r / 32, c = r % 32;
        w1tp[i] = (j < 75) ? W1[l * 2400 + c * 75 + j] : 0.f;
        w2p[i]  = (j < 75) ? W2[l * 2400 + j * 32 + c] : 0.f;
    } else if (i < 2 * HPAD * 32 + 2 * HPAD) {
        int k = i - 2 * HPAD * 32;
        int l = k / HPAD, j = k % HPAD;
        b1p[k] = (j < 75) ? b1[l * 75 + j] : 0.f;
    }
}

// ---------- bucket sort phase A ----------
__global__ void __launch_bounds__(256) ksA(const int* __restrict__ ei, int* __restrict__ cmat) {
    __shared__ int lh[NBKT];
    for (int i = threadIdx.x; i < NBKT; i += 256) lh[i] = 0;
    __syncthreads();
    int b0 = blockIdx.x * CHUNK;
    for (int i = threadIdx.x; i < CHUNK; i += 256) {
        int e = b0 + i;
        if (e < N_EDGES) atomicAdd(&lh[ei[N_EDGES + e] >> 6], 1);
    }
    __syncthreads();
    for (int b = threadIdx.x; b < NBKT; b += 256) cmat[b * NBLKA + blockIdx.x] = lh[b];
}

// ---------- parallel exclusive scan of cmat ----------
__global__ void ks1(const int* __restrict__ a, int* __restrict__ bs) {
    __shared__ int s[256];
    int i = blockIdx.x * 256 + threadIdx.x;
    s[threadIdx.x] = a[i];
    __syncthreads();
    for (int o = 128; o > 0; o >>= 1) {
        if (threadIdx.x < o) s[threadIdx.x] += s[threadIdx.x + o];
        __syncthreads();
    }
    if (threadIdx.x == 0) bs[blockIdx.x] = s[0];
}

__global__ void ks2(int* __restrict__ bs) {
    __shared__ int s[256];
    int t = threadIdx.x;
    int v[VPT];
    int base = t * VPT, sum = 0;
#pragma unroll
    for (int k = 0; k < VPT; k++) {
        int idx = base + k;
        int x = (idx < NS1) ? bs[idx] : 0;
        v[k] = sum; sum += x;
    }
    s[t] = sum;
    __syncthreads();
    for (int o = 1; o < 256; o <<= 1) {
        int add = (t >= o) ? s[t - o] : 0;
        __syncthreads();
        s[t] += add;
        __syncthreads();
    }
    int excl = (t == 0) ? 0 : s[t - 1];
#pragma unroll
    for (int k = 0; k < VPT; k++) {
        int idx = base + k;
        if (idx < NS1) bs[idx] = excl + v[k];
    }
}

__global__ void ks3(int* __restrict__ a, const int* __restrict__ bs) {
    __shared__ int s[256];
    int t = threadIdx.x, i = blockIdx.x * 256 + t;
    int v = a[i];
    s[t] = v;
    __syncthreads();
    for (int o = 1; o < 256; o <<= 1) {
        int add = (t >= o) ? s[t - o] : 0;
        __syncthreads();
        s[t] += add;
        __syncthreads();
    }
    a[i] = s[t] - v + bs[blockIdx.x];
}

// ---------- phase B: scatter records into bucket-grouped buf1 ----------
__global__ void __launch_bounds__(256) ksB(const int* __restrict__ ei, const float* __restrict__ ea,
                                           const int* __restrict__ cmat, float4* __restrict__ buf1) {
    __shared__ int base[NBKT];
    for (int i = threadIdx.x; i < NBKT; i += 256) base[i] = cmat[i * NBLKA + blockIdx.x];
    __syncthreads();
    int b0 = blockIdx.x * CHUNK;
    for (int i = threadIdx.x; i < CHUNK; i += 256) {
        int e = b0 + i;
        if (e >= N_EDGES) break;
        int src = ei[e], dst = ei[N_EDGES + e];
        float a0 = ea[(size_t)e * 3 + 0], a1 = ea[(size_t)e * 3 + 1], a2 = ea[(size_t)e * 3 + 2];
        int pos = atomicAdd(&base[dst >> 6], 1);
        buf1[pos] = make_float4(a0, a1, a2, __int_as_float(src | ((dst & 63) << 17)));
    }
}

// ---------- phase C: per-bucket exact CSR ----------
__global__ void __launch_bounds__(256) ksC(const int* __restrict__ cmat, const float4* __restrict__ buf1,
                                           float4* __restrict__ packed, int* __restrict__ offs) {
    __shared__ int cnt[64];
    __shared__ int excl[65];
    int g = blockIdx.x, t = threadIdx.x;
    int bb = cmat[g * NBLKA];
    int be = (g == NBKT - 1) ? N_EDGES : cmat[(g + 1) * NBLKA];
    if (t < 64) cnt[t] = 0;
    __syncthreads();
    for (int j = bb + t; j < be; j += 256) {
        int bits = __float_as_int(buf1[j].w);
        atomicAdd(&cnt[bits >> 17], 1);
    }
    __syncthreads();
    if (t == 0) {
        int a = 0;
        for (int i = 0; i < 64; i++) { excl[i] = a; a += cnt[i]; }
        excl[64] = a;
    }
    __syncthreads();
    if (t < 64) offs[g * 64 + t] = bb + excl[t];
    if (g == NBKT - 1 && t == 0) offs[NPAD] = N_EDGES;
    if (t < 64) cnt[t] = 0;
    __syncthreads();
    for (int j = bb + t; j < be; j += 256) {
        float4 r = buf1[j];
        int bits = __float_as_int(r.w);
        int dl = bits >> 17, src = bits & 0x1FFFF;
        int rank = atomicAdd(&cnt[dl], 1);
        packed[bb + excl[dl] + rank] = make_float4(r.x, r.y, r.z, __int_as_float(src));
    }
}

// ---------- pull aggregation: 32 threads/node (4-way edge split, 2 shfl combines) ----------
__global__ void __launch_bounds__(256) k_agg(const float4* __restrict__ packed,
                                             const int* __restrict__ offs,
                                             const float* __restrict__ eW, const float* __restrict__ eb,
                                             const float* __restrict__ h, float* __restrict__ agg) {
    int t = blockIdx.x * 256 + threadIdx.x;   // N_NODES*32 exact
    int n = t >> 5, s = t & 31;
    int q = s & 7, part = s >> 3;             // quad 0..7, edge-part 0..3
    int c0 = q * 4;
    float w0[4], w1[4], w2[4], bb4[4];
#pragma unroll
    for (int i = 0; i < 4; i++) {
        w0[i] = eW[c0 + i];
        w1[i] = eW[32 + c0 + i];
        w2[i] = eW[64 + c0 + i];
        bb4[i] = eb[c0 + i];
    }
    int beg = offs[n], end = offs[n + 1];
    float acc[4] = {0.f, 0.f, 0.f, 0.f};
    for (int j = beg + part; j < end; j += 4) {
        float4 p = packed[j];
        int src = __float_as_int(p.w);
        float4 hs = *(const float4*)(h + (size_t)src * 32 + c0);
        const float* hp = (const float*)&hs;
#pragma unroll
        for (int i = 0; i < 4; i++) {
            float m = hp[i] + p.x * w0[i] + p.y * w1[i] + p.z * w2[i] + bb4[i];
            acc[i] += fmaxf(m, 0.f);
        }
    }
#pragma unroll
    for (int i = 0; i < 4; i++) {
        acc[i] += __shfl_xor(acc[i], 8, 64);
        acc[i] += __shfl_xor(acc[i], 16, 64);
    }
    if (part == 0)
        *(float4*)(agg + (size_t)n * 32 + c0) = make_float4(acc[0], acc[1], acc[2], acc[3]);
}

// ---------- fused MLP: z = relu((h+agg)@W1+b1)@W2+b2, written over agg ----------
__global__ void __launch_bounds__(256, 4) k_mlp(const float* __restrict__ h, float* __restrict__ agg,
                                                const float* __restrict__ W1, const float* __restrict__ B1,
                                                const float* __restrict__ W2, const float* __restrict__ b2) {
    unsigned t = blockIdx.x * 256 + threadIdx.x;   // N_NODES*8 exact
    unsigned lane = threadIdx.x & 63;
    unsigned oct = lane >> 3;          // hidden-slice / output-quad index
    unsigned nd = lane & 7;            // node within this wave's 8-node group
    unsigned n = (t >> 6) * 8 + nd;    // 12500 waves * 8 nodes = N_NODES exact
    const float4* hp = (const float4*)(h + (size_t)n * 32);
    const float4* ap = (const float4*)(agg + (size_t)n * 32);
    float zc[32];
#pragma unroll
    for (int q = 0; q < 8; q++) {
        float4 hv = hp[q], av = ap[q];
        zc[q * 4 + 0] = hv.x + av.x;
        zc[q * 4 + 1] = hv.y + av.y;
        zc[q * 4 + 2] = hv.z + av.z;
        zc[q * 4 + 3] = hv.w + av.w;
    }
    float hid[10];
#pragma unroll
    for (int i = 0; i < 10; i++) {
        int j = (int)oct * 10 + i;
        const float4* wp = (const float4*)(W1 + j * 32);
        float a0 = 0.f, a1 = 0.f, a2 = 0.f, a3 = 0.f;
#pragma unroll
        for (int q = 0; q < 8; q++) {
            float4 wv = wp[q];
            a0 += zc[q * 4 + 0] * wv.x;
            a1 += zc[q * 4 + 1] * wv.y;
            a2 += zc[q * 4 + 2] * wv.z;
            a3 += zc[q * 4 + 3] * wv.w;
        }
        hid[i] = fmaxf(B1[j] + ((a0 + a1) + (a2 + a3)), 0.f);
    }
    float4 zo = *(const float4*)(b2 + oct * 4);
#pragma unroll
    for (int p = 0; p < 8; p++) {
        int srcl = (int)nd | (p << 3);
#pragma unroll
        for (int i = 0; i < 10; i++) {
            float hj = __shfl(hid[i], srcl, 64);
            float4 wv = *(const float4*)(W2 + (p * 10 + i) * 32 + oct * 4);
            zo.x += hj * wv.x;
            zo.y += hj * wv.y;
            zo.z += hj * wv.z;
            zo.w += hj * wv.w;
        }
    }
    *(float4*)(agg + (size_t)n * 32 + oct * 4) = zo;
}

// ---------- BN stats ----------
__global__ void __launch_bounds__(256) k_stats(const float* __restrict__ z, float* __restrict__ stats) {
    __shared__ float ls[4 * 64];
    int tid = threadIdx.x;
    int c = tid & 31;
    float s = 0.f, s2 = 0.f;
    for (int e = blockIdx.x * 256 + tid; e < N_NODES * 32; e += 256 * 256) {
        float v = z[e];
        s += v; s2 += v * v;
    }
    s += __shfl_down(s, 32, 64);
    s2 += __shfl_down(s2, 32, 64);
    int wave = tid >> 6, lane = tid & 63;
    if (lane < 32) { ls[wave * 64 + c] = s; ls[wave * 64 + 32 + c] = s2; }
    __syncthreads();
    if (tid < 64) {
        float a = ls[tid] + ls[64 + tid] + ls[128 + tid] + ls[192 + tid];
        atomicAdd(&stats[tid], a);
    }
}

// ---------- BN apply + relu ----------
__global__ void k_bn(const float* __restrict__ z, float* __restrict__ h,
                     const float* __restrict__ stats, const float* __restrict__ g,
                     const float* __restrict__ b) {
    int t = blockIdx.x * 256 + threadIdx.x;
    if (t >= N_NODES * 8) return;
    int q = t & 7;
    float4 zv = ((const float4*)z)[t];
    float* zp = (float*)&zv;
    float4 ov;
    float* op = (float*)&ov;
    const float invN = 1.0f / (float)N_NODES;
#pragma unroll
    for (int i = 0; i < 4; i++) {
        int c = q * 4 + i;
        float mu = stats[c] * invN;
        float var = stats[32 + c] * invN - mu * mu;
        float sc = g[c] / sqrtf(var + BN_EPS);
        op[i] = fmaxf((zp[i] - mu) * sc + b[c], 0.f);
    }
    ((float4*)h)[t] = ov;
}

// ---------- graph offsets (batch is sorted) ----------
__global__ void k_goff(const int* __restrict__ batch, int* __restrict__ goff) {
    int g = blockIdx.x * 256 + threadIdx.x;
    if (g > N_GRAPHS) return;
    int lo = 0, hi = N_NODES;
    while (lo < hi) {
        int mid = (lo + hi) >> 1;
        if (batch[mid] < g) lo = mid + 1; else hi = mid;
    }
    goff[g] = lo;
}

// ---------- mean-pool: one wave per graph ----------
__global__ void __launch_bounds__(256) k_pool2(const float* __restrict__ h, const int* __restrict__ goff,
                                               float* __restrict__ gsum) {
    int wid = threadIdx.x >> 6, lane = threadIdx.x & 63;
    int g = blockIdx.x * 4 + wid;
    if (g >= N_GRAPHS) return;
    int s = goff[g], e = goff[g + 1];
    int c = lane & 31, half = lane >> 5;
    float acc = 0.f;
    for (int n = s + half; n < e; n += 2) acc += h[(size_t)n * 32 + c];
    acc += __shfl_down(acc, 32, 64);
    if (lane < 32) gsum[(size_t)g * 32 + c] = acc;
}

__global__ void k_head(const float* __restrict__ gsum, const int* __restrict__ goff,
                       const float* __restrict__ W1, const float* __restrict__ b1,
                       const float* __restrict__ W2, const float* __restrict__ b2,
                       float* __restrict__ out) {
    __shared__ float sW1[512], sb1[16], sW2[32], sb2[2];
    for (int i = threadIdx.x; i < 512; i += 256) sW1[i] = W1[i];
    if (threadIdx.x < 16) sb1[threadIdx.x] = b1[threadIdx.x];
    if (threadIdx.x < 32) sW2[threadIdx.x] = W2[threadIdx.x];
    if (threadIdx.x < 2) sb2[threadIdx.x] = b2[threadIdx.x];
    __syncthreads();
    int gI = blockIdx.x * 256 + threadIdx.x;
    if (gI >= N_GRAPHS) return;
    float cnt = (float)(goff[gI + 1] - goff[gI]);
    float inv = 1.0f / fmaxf(cnt, 1.0f);
    float gx[32];
#pragma unroll
    for (int c = 0; c < 32; c++) gx[c] = gsum[(size_t)gI * 32 + c] * inv;
    float hid[16];
#pragma unroll
    for (int j = 0; j < 16; j++) {
        float a = sb1[j];
#pragma unroll
        for (int c = 0; c < 32; c++) a += gx[c] * sW1[c * 16 + j];
        hid[j] = fmaxf(a, 0.f);
    }
#pragma unroll
    for (int o = 0; o < 2; o++) {
        float a = sb2[o];
#pragma unroll
        for (int j = 0; j < 16; j++) a += hid[j] * sW2[j * 2 + o];
        out[(size_t)gI * 2 + o] = a;
    }
}

extern "C" void kernel_launch(void* const* d_in, const int* in_sizes, int n_in,
                              void* d_out, int out_size, void* d_ws, size_t ws_size,
                              hipStream_t stream) {
    const float* x       = (const float*)d_in[0];
    const int*   ei      = (const int*)d_in[1];
    const float* eattr   = (const float*)d_in[2];
    const int*   batch   = (const int*)d_in[3];
    const float* node_w  = (const float*)d_in[4];
    const float* node_b  = (const float*)d_in[5];
    const float* edge_w  = (const float*)d_in[6];
    const float* edge_b  = (const float*)d_in[7];
    const float* conv_w1 = (const float*)d_in[8];
    const float* conv_b1 = (const float*)d_in[9];
    const float* conv_w2 = (const float*)d_in[10];
    const float* conv_b2 = (const float*)d_in[11];
    const float* bn_g    = (const float*)d_in[12];
    const float* bn_b    = (const float*)d_in[13];
    const float* lin1_w  = (const float*)d_in[14];
    const float* lin1_b  = (const float*)d_in[15];
    const float* lin2_w  = (const float*)d_in[16];
    const float* lin2_b  = (const float*)d_in[17];
    float* out = (float*)d_out;

    float4* packed = (float4*)d_ws;                        // 51.2 MB
    float4* buf1   = packed + N_EDGES;                     // 51.2 MB (CSR build only)
    float*  h      = (float*)(buf1 + N_EDGES);             // 12.8 MB
    float*  agg    = h + (size_t)N_NODES * 32;             // 12.8 MB (z in-place)
    int*    cmat   = (int*)(agg + (size_t)N_NODES * 32);   // LALLOC ints
    int*    t1     = cmat + LALLOC;                        // 2560
    int*    offs   = t1 + 2560;                            // NPAD+1
    int*    goff   = offs + NPAD + 1;                      // N_GRAPHS+1
    float*  stats  = (float*)(goff + N_GRAPHS + 1);        // 64
    float*  gsum   = stats + 64;                           // G*32
    float*  w1tp   = gsum + (size_t)N_GRAPHS * 32;         // 2*80*32
    float*  b1p    = w1tp + 2 * HPAD * 32;                 // 2*80
    float*  w2p    = b1p + 2 * HPAD;                       // 2*80*32

    int nb_nodes = (N_NODES + 255) / 256;
    int nb_vec   = (N_NODES * 8 + 255) / 256;

    hipMemsetAsync(cmat, 0, LALLOC * sizeof(int), stream);
    k_encode<<<nb_nodes, 256, 0, stream>>>(x, node_w, node_b, h);
    k_prep<<<(2 * HPAD * 32 + 2 * HPAD + 255) / 256, 256, 0, stream>>>(
        conv_w1, conv_b1, conv_w2, w1tp, b1p, w2p);
    k_goff<<<(N_GRAPHS + 1 + 255) / 256, 256, 0, stream>>>(batch, goff);

    ksA<<<NBLKA, 256, 0, stream>>>(ei, cmat);
    ks1<<<NS1, 256, 0, stream>>>(cmat, t1);
    ks2<<<1, 256, 0, stream>>>(t1);
    ks3<<<NS1, 256, 0, stream>>>(cmat, t1);
    ksB<<<NBLKA, 256, 0, stream>>>(ei, eattr, cmat, buf1);
    ksC<<<NBKT, 256, 0, stream>>>(cmat, buf1, packed, offs);

    for (int l = 0; l < 2; l++) {
        hipMemsetAsync(stats, 0, 64 * sizeof(float), stream);
        k_agg<<<N_NODES * 32 / 256, 256, 0, stream>>>(packed, offs, edge_w, edge_b, h, agg);
        k_mlp<<<N_NODES * 8 / 256, 256, 0, stream>>>(h, agg, w1tp + l * HPAD * 32,
                                                     b1p + l * HPAD, w2p + l * HPAD * 32,
                                                     conv_b2 + l * 32);
        k_stats<<<256, 256, 0, stream>>>(agg, stats);
        k_bn<<<nb_vec, 256, 0, stream>>>(agg, h, stats, bn_g + l * 32, bn_b + l * 32);
    }
    k_pool2<<<(N_GRAPHS + 3) / 4, 256, 0, stream>>>(h, goff, gsum);
    k_head<<<(N_GRAPHS + 255) / 256, 256, 0, stream>>>(gsum, goff, lin1_w, lin1_b, lin2_w, lin2_b, out);
}

// Round 12
// 669.882 us; speedup vs baseline: 2.5204x; 1.0015x over previous
//
#include <hip/hip_runtime.h>

#define N_NODES 100000
#define N_EDGES 3200000
#define N_GRAPHS 5000
#define BN_EPS 1e-5f
#define HPAD 80        // hidden 75 padded to 80
#define CHUNK 4096     // edges per bucket-sort block
#define NBLKA 782      // ceil(N_EDGES / CHUNK)
#define NBKT 196       // buckets of 512 nodes (dst >> 9)
#define NPAD2 (NBKT * 512)   // 100352
#define NS1 599        // ceil(NBKT*NBLKA / 256) = ceil(153272/256)
#define LALLOC (NS1 * 256)   // 153344
#define VPT 3          // ceil(NS1 / 256) for ks2

// ---------- node encoder: h = x @ node_w + node_b ----------
__global__ void k_encode(const float* __restrict__ x, const float* __restrict__ W,
                         const float* __restrict__ b, float* __restrict__ h) {
    __shared__ float sW[448];
    __shared__ float sb[32];
    for (int i = threadIdx.x; i < 448; i += 256) sW[i] = W[i];
    if (threadIdx.x < 32) sb[threadIdx.x] = b[threadIdx.x];
    __syncthreads();
    int n = blockIdx.x * 256 + threadIdx.x;
    if (n >= N_NODES) return;
    float xi[14];
#pragma unroll
    for (int k = 0; k < 14; k++) xi[k] = x[n * 14 + k];
    float4* hp = (float4*)(h + (size_t)n * 32);
#pragma unroll
    for (int q = 0; q < 8; q++) {
        float4 acc;
        float* ap = (float*)&acc;
#pragma unroll
        for (int i = 0; i < 4; i++) {
            int c = q * 4 + i;
            float a = sb[c];
#pragma unroll
            for (int k = 0; k < 14; k++) a += xi[k] * sW[k * 32 + c];
            ap[i] = a;
        }
        hp[q] = acc;
    }
}

// ---------- weight prep ----------
__global__ void k_prep(const float* __restrict__ W1, const float* __restrict__ b1,
                       const float* __restrict__ W2,
                       float* __restrict__ w1tp, float* __restrict__ b1p,
                       float* __restrict__ w2p) {
    int i = blockIdx.x * 256 + threadIdx.x;
    if (i < 2 * HPAD * 32) {
        int l = i / (HPAD * 32), r = i % (HPAD * 32);
        int j = r / 32, c = r % 32;
        w1tp[i] = (j < 75) ? W1[l * 2400 + c * 75 + j] : 0.f;
        w2p[i]  = (j < 75) ? W2[l * 2400 + j * 32 + c] : 0.f;
    } else if (i < 2 * HPAD * 32 + 2 * HPAD) {
        int k = i - 2 * HPAD * 32;
        int l = k / HPAD, j = k % HPAD;
        b1p[k] = (j < 75) ? b1[l * 75 + j] : 0.f;
    }
}

// ---------- bucket sort phase A: 196-bucket per-block histogram ----------
__global__ void __launch_bounds__(256) ksA(const int* __restrict__ ei, int* __restrict__ cmat) {
    __shared__ int lh[NBKT];
    if (threadIdx.x < NBKT) lh[threadIdx.x] = 0;
    __syncthreads();
    int b0 = blockIdx.x * CHUNK;
    for (int i = threadIdx.x; i < CHUNK; i += 256) {
        int e = b0 + i;
        if (e < N_EDGES) atomicAdd(&lh[ei[N_EDGES + e] >> 9], 1);
    }
    __syncthreads();
    if (threadIdx.x < NBKT) cmat[threadIdx.x * NBLKA + blockIdx.x] = lh[threadIdx.x];
}

// ---------- parallel exclusive scan of cmat ----------
__global__ void ks1(const int* __restrict__ a, int* __restrict__ bs) {
    __shared__ int s[256];
    int i = blockIdx.x * 256 + threadIdx.x;
    s[threadIdx.x] = a[i];
    __syncthreads();
    for (int o = 128; o > 0; o >>= 1) {
        if (threadIdx.x < o) s[threadIdx.x] += s[threadIdx.x + o];
        __syncthreads();
    }
    if (threadIdx.x == 0) bs[blockIdx.x] = s[0];
}

__global__ void ks2(int* __restrict__ bs) {
    __shared__ int s[256];
    int t = threadIdx.x;
    int v[VPT];
    int base = t * VPT, sum = 0;
#pragma unroll
    for (int k = 0; k < VPT; k++) {
        int idx = base + k;
        int x = (idx < NS1) ? bs[idx] : 0;
        v[k] = sum; sum += x;
    }
    s[t] = sum;
    __syncthreads();
    for (int o = 1; o < 256; o <<= 1) {
        int add = (t >= o) ? s[t - o] : 0;
        __syncthreads();
        s[t] += add;
        __syncthreads();
    }
    int excl = (t == 0) ? 0 : s[t - 1];
#pragma unroll
    for (int k = 0; k < VPT; k++) {
        int idx = base + k;
        if (idx < NS1) bs[idx] = excl + v[k];
    }
}

__global__ void ks3(int* __restrict__ a, const int* __restrict__ bs) {
    __shared__ int s[256];
    int t = threadIdx.x, i = blockIdx.x * 256 + t;
    int v = a[i];
    s[t] = v;
    __syncthreads();
    for (int o = 1; o < 256; o <<= 1) {
        int add = (t >= o) ? s[t - o] : 0;
        __syncthreads();
        s[t] += add;
        __syncthreads();
    }
    a[i] = s[t] - v + bs[blockIdx.x];
}

// ---------- phase B: scatter records into 196-bucket-grouped buf1 ----------
__global__ void __launch_bounds__(256) ksB(const int* __restrict__ ei, const float* __restrict__ ea,
                                           const int* __restrict__ cmat, float4* __restrict__ buf1) {
    __shared__ int base[NBKT];
    if (threadIdx.x < NBKT) base[threadIdx.x] = cmat[threadIdx.x * NBLKA + blockIdx.x];
    __syncthreads();
    int b0 = blockIdx.x * CHUNK;
    for (int i = threadIdx.x; i < CHUNK; i += 256) {
        int e = b0 + i;
        if (e >= N_EDGES) break;
        int src = ei[e], dst = ei[N_EDGES + e];
        float a0 = ea[(size_t)e * 3 + 0], a1 = ea[(size_t)e * 3 + 1], a2 = ea[(size_t)e * 3 + 2];
        int pos = atomicAdd(&base[dst >> 9], 1);
        buf1[pos] = make_float4(a0, a1, a2, __int_as_float(src | ((dst & 511) << 17)));
    }
}

// ---------- phase C: per-512-node-bucket exact CSR (1024-thread blocks) ----------
__global__ void __launch_bounds__(1024) ksC(const int* __restrict__ cmat, const float4* __restrict__ buf1,
                                            float4* __restrict__ packed, int* __restrict__ offs) {
    __shared__ int cnt[512];
    __shared__ int sc[512];
    __shared__ int excl[513];
    int g = blockIdx.x, t = threadIdx.x;
    int bb = cmat[g * NBLKA];
    int be = (g == NBKT - 1) ? N_EDGES : cmat[(g + 1) * NBLKA];
    if (t < 512) cnt[t] = 0;
    __syncthreads();
    for (int j = bb + t; j < be; j += 1024) {
        int bits = __float_as_int(buf1[j].w);
        atomicAdd(&cnt[bits >> 17], 1);
    }
    __syncthreads();
    if (t < 512) sc[t] = cnt[t];
    __syncthreads();
    for (int o = 1; o < 512; o <<= 1) {
        int add = 0;
        if (t < 512 && t >= o) add = sc[t - o];
        __syncthreads();
        if (t < 512) sc[t] += add;
        __syncthreads();
    }
    if (t < 512) excl[t] = sc[t] - cnt[t];
    if (t == 511) excl[512] = sc[511];
    __syncthreads();
    if (t < 512) offs[g * 512 + t] = bb + excl[t];
    if (g == NBKT - 1 && t == 0) offs[NPAD2] = N_EDGES;
    if (t < 512) cnt[t] = 0;
    __syncthreads();
    for (int j = bb + t; j < be; j += 1024) {
        float4 r = buf1[j];
        int bits = __float_as_int(r.w);
        int dl = bits >> 17, src = bits & 0x1FFFF;
        int rank = atomicAdd(&cnt[dl], 1);
        packed[bb + excl[dl] + rank] = make_float4(r.x, r.y, r.z, __int_as_float(src));
    }
}

// ---------- pull aggregation: 32 threads/node (4-way edge split, 2 shfl combines) ----------
__global__ void __launch_bounds__(256) k_agg(const float4* __restrict__ packed,
                                             const int* __restrict__ offs,
                                             const float* __restrict__ eW, const float* __restrict__ eb,
                                             const float* __restrict__ h, float* __restrict__ agg) {
    int t = blockIdx.x * 256 + threadIdx.x;   // N_NODES*32 exact
    int n = t >> 5, s = t & 31;
    int q = s & 7, part = s >> 3;             // quad 0..7, edge-part 0..3
    int c0 = q * 4;
    float w0[4], w1[4], w2[4], bb4[4];
#pragma unroll
    for (int i = 0; i < 4; i++) {
        w0[i] = eW[c0 + i];
        w1[i] = eW[32 + c0 + i];
        w2[i] = eW[64 + c0 + i];
        bb4[i] = eb[c0 + i];
    }
    int beg = offs[n], end = offs[n + 1];
    float acc[4] = {0.f, 0.f, 0.f, 0.f};
    for (int j = beg + part; j < end; j += 4) {
        float4 p = packed[j];
        int src = __float_as_int(p.w);
        float4 hs = *(const float4*)(h + (size_t)src * 32 + c0);
        const float* hp = (const float*)&hs;
#pragma unroll
        for (int i = 0; i < 4; i++) {
            float m = hp[i] + p.x * w0[i] + p.y * w1[i] + p.z * w2[i] + bb4[i];
            acc[i] += fmaxf(m, 0.f);
        }
    }
#pragma unroll
    for (int i = 0; i < 4; i++) {
        acc[i] += __shfl_xor(acc[i], 8, 64);
        acc[i] += __shfl_xor(acc[i], 16, 64);
    }
    if (part == 0)
        *(float4*)(agg + (size_t)n * 32 + c0) = make_float4(acc[0], acc[1], acc[2], acc[3]);
}

// ---------- fused MLP + BN stats: z = relu((h+agg)@W1+b1)@W2+b2 over agg; sum/sumsq -> stats ----------
__global__ void __launch_bounds__(256, 4) k_mlp(const float* __restrict__ h, float* __restrict__ agg,
                                                const float* __restrict__ W1, const float* __restrict__ B1,
                                                const float* __restrict__ W2, const float* __restrict__ b2,
                                                float* __restrict__ stats) {
    __shared__ float bstat[64];
    if (threadIdx.x < 64) bstat[threadIdx.x] = 0.f;
    __syncthreads();
    unsigned t = blockIdx.x * 256 + threadIdx.x;   // N_NODES*8 exact
    unsigned lane = threadIdx.x & 63;
    unsigned oct = lane >> 3;          // hidden-slice / output-quad index
    unsigned nd = lane & 7;            // node within this wave's 8-node group
    unsigned n = (t >> 6) * 8 + nd;    // 12500 waves * 8 nodes = N_NODES exact
    const float4* hp = (const float4*)(h + (size_t)n * 32);
    const float4* ap = (const float4*)(agg + (size_t)n * 32);
    float zc[32];
#pragma unroll
    for (int q = 0; q < 8; q++) {
        float4 hv = hp[q], av = ap[q];
        zc[q * 4 + 0] = hv.x + av.x;
        zc[q * 4 + 1] = hv.y + av.y;
        zc[q * 4 + 2] = hv.z + av.z;
        zc[q * 4 + 3] = hv.w + av.w;
    }
    float hid[10];
#pragma unroll
    for (int i = 0; i < 10; i++) {
        int j = (int)oct * 10 + i;
        const float4* wp = (const float4*)(W1 + j * 32);
        float a0 = 0.f, a1 = 0.f, a2 = 0.f, a3 = 0.f;
#pragma unroll
        for (int q = 0; q < 8; q++) {
            float4 wv = wp[q];
            a0 += zc[q * 4 + 0] * wv.x;
            a1 += zc[q * 4 + 1] * wv.y;
            a2 += zc[q * 4 + 2] * wv.z;
            a3 += zc[q * 4 + 3] * wv.w;
        }
        hid[i] = fmaxf(B1[j] + ((a0 + a1) + (a2 + a3)), 0.f);
    }
    float4 zo = *(const float4*)(b2 + oct * 4);
#pragma unroll
    for (int p = 0; p < 8; p++) {
        int srcl = (int)nd | (p << 3);
#pragma unroll
        for (int i = 0; i < 10; i++) {
            float hj = __shfl(hid[i], srcl, 64);
            float4 wv = *(const float4*)(W2 + (p * 10 + i) * 32 + oct * 4);
            zo.x += hj * wv.x;
            zo.y += hj * wv.y;
            zo.z += hj * wv.z;
            zo.w += hj * wv.w;
        }
    }
    *(float4*)(agg + (size_t)n * 32 + oct * 4) = zo;
    // BN stats: reduce over the 8 nodes in this wave-group (shfl_xor over nd bits)
    float s0 = zo.x, s1 = zo.y, s2v = zo.z, s3 = zo.w;
    float q0 = zo.x * zo.x, q1 = zo.y * zo.y, q2 = zo.z * zo.z, q3 = zo.w * zo.w;
#pragma unroll
    for (int m = 1; m < 8; m <<= 1) {
        s0 += __shfl_xor(s0, m, 64);
        s1 += __shfl_xor(s1, m, 64);
        s2v += __shfl_xor(s2v, m, 64);
        s3 += __shfl_xor(s3, m, 64);
        q0 += __shfl_xor(q0, m, 64);
        q1 += __shfl_xor(q1, m, 64);
        q2 += __shfl_xor(q2, m, 64);
        q3 += __shfl_xor(q3, m, 64);
    }
    if (nd == 0) {
        int c0 = (int)oct * 4;
        atomicAdd(&bstat[c0 + 0], s0);
        atomicAdd(&bstat[c0 + 1], s1);
        atomicAdd(&bstat[c0 + 2], s2v);
        atomicAdd(&bstat[c0 + 3], s3);
        atomicAdd(&bstat[32 + c0 + 0], q0);
        atomicAdd(&bstat[32 + c0 + 1], q1);
        atomicAdd(&bstat[32 + c0 + 2], q2);
        atomicAdd(&bstat[32 + c0 + 3], q3);
    }
    __syncthreads();
    if (threadIdx.x < 64) atomicAdd(&stats[threadIdx.x], bstat[threadIdx.x]);
}

// ---------- BN apply + relu ----------
__global__ void k_bn(const float* __restrict__ z, float* __restrict__ h,
                     const float* __restrict__ stats, const float* __restrict__ g,
                     const float* __restrict__ b) {
    int t = blockIdx.x * 256 + threadIdx.x;
    if (t >= N_NODES * 8) return;
    int q = t & 7;
    float4 zv = ((const float4*)z)[t];
    float* zp = (float*)&zv;
    float4 ov;
    float* op = (float*)&ov;
    const float invN = 1.0f / (float)N_NODES;
#pragma unroll
    for (int i = 0; i < 4; i++) {
        int c = q * 4 + i;
        float mu = stats[c] * invN;
        float var = stats[32 + c] * invN - mu * mu;
        float sc = g[c] / sqrtf(var + BN_EPS);
        op[i] = fmaxf((zp[i] - mu) * sc + b[c], 0.f);
    }
    ((float4*)h)[t] = ov;
}

// ---------- graph offsets (batch is sorted) ----------
__global__ void k_goff(const int* __restrict__ batch, int* __restrict__ goff) {
    int g = blockIdx.x * 256 + threadIdx.x;
    if (g > N_GRAPHS) return;
    int lo = 0, hi = N_NODES;
    while (lo < hi) {
        int mid = (lo + hi) >> 1;
        if (batch[mid] < g) lo = mid + 1; else hi = mid;
    }
    goff[g] = lo;
}

// ---------- mean-pool: one wave per graph ----------
__global__ void __launch_bounds__(256) k_pool2(const float* __restrict__ h, const int* __restrict__ goff,
                                               float* __restrict__ gsum) {
    int wid = threadIdx.x >> 6, lane = threadIdx.x & 63;
    int g = blockIdx.x * 4 + wid;
    if (g >= N_GRAPHS) return;
    int s = goff[g], e = goff[g + 1];
    int c = lane & 31, half = lane >> 5;
    float acc = 0.f;
    for (int n = s + half; n < e; n += 2) acc += h[(size_t)n * 32 + c];
    acc += __shfl_down(acc, 32, 64);
    if (lane < 32) gsum[(size_t)g * 32 + c] = acc;
}

__global__ void k_head(const float* __restrict__ gsum, const int* __restrict__ goff,
                       const float* __restrict__ W1, const float* __restrict__ b1,
                       const float* __restrict__ W2, const float* __restrict__ b2,
                       float* __restrict__ out) {
    __shared__ float sW1[512], sb1[16], sW2[32], sb2[2];
    for (int i = threadIdx.x; i < 512; i += 256) sW1[i] = W1[i];
    if (threadIdx.x < 16) sb1[threadIdx.x] = b1[threadIdx.x];
    if (threadIdx.x < 32) sW2[threadIdx.x] = W2[threadIdx.x];
    if (threadIdx.x < 2) sb2[threadIdx.x] = b2[threadIdx.x];
    __syncthreads();
    int gI = blockIdx.x * 256 + threadIdx.x;
    if (gI >= N_GRAPHS) return;
    float cnt = (float)(goff[gI + 1] - goff[gI]);
    float inv = 1.0f / fmaxf(cnt, 1.0f);
    float gx[32];
#pragma unroll
    for (int c = 0; c < 32; c++) gx[c] = gsum[(size_t)gI * 32 + c] * inv;
    float hid[16];
#pragma unroll
    for (int j = 0; j < 16; j++) {
        float a = sb1[j];
#pragma unroll
        for (int c = 0; c < 32; c++) a += gx[c] * sW1[c * 16 + j];
        hid[j] = fmaxf(a, 0.f);
    }
#pragma unroll
    for (int o = 0; o < 2; o++) {
        float a = sb2[o];
#pragma unroll
        for (int j = 0; j < 16; j++) a += hid[j] * sW2[j * 2 + o];
        out[(size_t)gI * 2 + o] = a;
    }
}

extern "C" void kernel_launch(void* const* d_in, const int* in_sizes, int n_in,
                              void* d_out, int out_size, void* d_ws, size_t ws_size,
                              hipStream_t stream) {
    const float* x       = (const float*)d_in[0];
    const int*   ei      = (const int*)d_in[1];
    const float* eattr   = (const float*)d_in[2];
    const int*   batch   = (const int*)d_in[3];
    const float* node_w  = (const float*)d_in[4];
    const float* node_b  = (const float*)d_in[5];
    const float* edge_w  = (const float*)d_in[6];
    const float* edge_b  = (const float*)d_in[7];
    const float* conv_w1 = (const float*)d_in[8];
    const float* conv_b1 = (const float*)d_in[9];
    const float* conv_w2 = (const float*)d_in[10];
    const float* conv_b2 = (const float*)d_in[11];
    const float* bn_g    = (const float*)d_in[12];
    const float* bn_b    = (const float*)d_in[13];
    const float* lin1_w  = (const float*)d_in[14];
    const float* lin1_b  = (const float*)d_in[15];
    const float* lin2_w  = (const float*)d_in[16];
    const float* lin2_b  = (const float*)d_in[17];
    float* out = (float*)d_out;

    float4* packed = (float4*)d_ws;                        // 51.2 MB
    float4* buf1   = packed + N_EDGES;                     // 51.2 MB (CSR build only)
    float*  h      = (float*)(buf1 + N_EDGES);             // 12.8 MB
    float*  agg    = h + (size_t)N_NODES * 32;             // 12.8 MB (z in-place)
    int*    cmat   = (int*)(agg + (size_t)N_NODES * 32);   // LALLOC ints
    int*    t1     = cmat + LALLOC;                        // 768
    int*    offs   = t1 + 768;                             // NPAD2+1
    int*    goff   = offs + NPAD2 + 1;                     // N_GRAPHS+1
    float*  stats  = (float*)(goff + N_GRAPHS + 1);        // 64
    float*  gsum   = stats + 64;                           // G*32
    float*  w1tp   = gsum + (size_t)N_GRAPHS * 32;         // 2*80*32
    float*  b1p    = w1tp + 2 * HPAD * 32;                 // 2*80
    float*  w2p    = b1p + 2 * HPAD;                       // 2*80*32

    int nb_nodes = (N_NODES + 255) / 256;
    int nb_vec   = (N_NODES * 8 + 255) / 256;

    hipMemsetAsync(cmat, 0, LALLOC * sizeof(int), stream);
    k_encode<<<nb_nodes, 256, 0, stream>>>(x, node_w, node_b, h);
    k_prep<<<(2 * HPAD * 32 + 2 * HPAD + 255) / 256, 256, 0, stream>>>(
        conv_w1, conv_b1, conv_w2, w1tp, b1p, w2p);
    k_goff<<<(N_GRAPHS + 1 + 255) / 256, 256, 0, stream>>>(batch, goff);

    ksA<<<NBLKA, 256, 0, stream>>>(ei, cmat);
    ks1<<<NS1, 256, 0, stream>>>(cmat, t1);
    ks2<<<1, 256, 0, stream>>>(t1);
    ks3<<<NS1, 256, 0, stream>>>(cmat, t1);
    ksB<<<NBLKA, 256, 0, stream>>>(ei, eattr, cmat, buf1);
    ksC<<<NBKT, 1024, 0, stream>>>(cmat, buf1, packed, offs);

    for (int l = 0; l < 2; l++) {
        hipMemsetAsync(stats, 0, 64 * sizeof(float), stream);
        k_agg<<<N_NODES * 32 / 256, 256, 0, stream>>>(packed, offs, edge_w, edge_b, h, agg);
        k_mlp<<<N_NODES * 8 / 256, 256, 0, stream>>>(h, agg, w1tp + l * HPAD * 32,
                                                     b1p + l * HPAD, w2p + l * HPAD * 32,
                                                     conv_b2 + l * 32, stats);
        k_bn<<<nb_vec, 256, 0, stream>>>(agg, h, stats, bn_g + l * 32, bn_b + l * 32);
    }
    k_pool2<<<(N_GRAPHS + 3) / 4, 256, 0, stream>>>(h, goff, gsum);
    k_head<<<(N_GRAPHS + 255) / 256, 256, 0, stream>>>(gsum, goff, lin1_w, lin1_b, lin2_w, lin2_b, out);
}

// Round 13
// 625.192 us; speedup vs baseline: 2.7006x; 1.0715x over previous
//
#include <hip/hip_runtime.h>

#define N_NODES 100000
#define N_EDGES 3200000
#define N_GRAPHS 5000
#define BN_EPS 1e-5f
#define HPAD 80        // hidden 75 padded to 80
#define CHUNK 4096     // edges per bucket-sort block
#define NBLKA 782      // ceil(N_EDGES / CHUNK)
#define NBKT 196       // buckets of 512 nodes (dst >> 9)
#define NPAD2 (NBKT * 512)   // 100352
#define NS1 599        // ceil(NBKT*NBLKA / 256)
#define LALLOC (NS1 * 256)
#define VPT 3          // ceil(NS1 / 256) for ks2

// ---------- node encoder: h = x @ node_w + node_b ----------
__global__ void k_encode(const float* __restrict__ x, const float* __restrict__ W,
                         const float* __restrict__ b, float* __restrict__ h) {
    __shared__ float sW[448];
    __shared__ float sb[32];
    for (int i = threadIdx.x; i < 448; i += 256) sW[i] = W[i];
    if (threadIdx.x < 32) sb[threadIdx.x] = b[threadIdx.x];
    __syncthreads();
    int n = blockIdx.x * 256 + threadIdx.x;
    if (n >= N_NODES) return;
    float xi[14];
#pragma unroll
    for (int k = 0; k < 14; k++) xi[k] = x[n * 14 + k];
    float4* hp = (float4*)(h + (size_t)n * 32);
#pragma unroll
    for (int q = 0; q < 8; q++) {
        float4 acc;
        float* ap = (float*)&acc;
#pragma unroll
        for (int i = 0; i < 4; i++) {
            int c = q * 4 + i;
            float a = sb[c];
#pragma unroll
            for (int k = 0; k < 14; k++) a += xi[k] * sW[k * 32 + c];
            ap[i] = a;
        }
        hp[q] = acc;
    }
}

// ---------- weight prep ----------
__global__ void k_prep(const float* __restrict__ W1, const float* __restrict__ b1,
                       const float* __restrict__ W2,
                       float* __restrict__ w1tp, float* __restrict__ b1p,
                       float* __restrict__ w2p) {
    int i = blockIdx.x * 256 + threadIdx.x;
    if (i < 2 * HPAD * 32) {
        int l = i / (HPAD * 32), r = i % (HPAD * 32);
        int j = r / 32, c = r % 32;
        w1tp[i] = (j < 75) ? W1[l * 2400 + c * 75 + j] : 0.f;
        w2p[i]  = (j < 75) ? W2[l * 2400 + j * 32 + c] : 0.f;
    } else if (i < 2 * HPAD * 32 + 2 * HPAD) {
        int k = i - 2 * HPAD * 32;
        int l = k / HPAD, j = k % HPAD;
        b1p[k] = (j < 75) ? b1[l * 75 + j] : 0.f;
    }
}

// ---------- bucket sort phase A: 196-bucket per-block histogram ----------
__global__ void __launch_bounds__(256) ksA(const int* __restrict__ ei, int* __restrict__ cmat) {
    __shared__ int lh[NBKT];
    if (threadIdx.x < NBKT) lh[threadIdx.x] = 0;
    __syncthreads();
    int b0 = blockIdx.x * CHUNK;
    for (int i = threadIdx.x; i < CHUNK; i += 256) {
        int e = b0 + i;
        if (e < N_EDGES) atomicAdd(&lh[ei[N_EDGES + e] >> 9], 1);
    }
    __syncthreads();
    if (threadIdx.x < NBKT) cmat[threadIdx.x * NBLKA + blockIdx.x] = lh[threadIdx.x];
}

// ---------- parallel exclusive scan of cmat ----------
__global__ void ks1(const int* __restrict__ a, int* __restrict__ bs) {
    __shared__ int s[256];
    int i = blockIdx.x * 256 + threadIdx.x;
    s[threadIdx.x] = a[i];
    __syncthreads();
    for (int o = 128; o > 0; o >>= 1) {
        if (threadIdx.x < o) s[threadIdx.x] += s[threadIdx.x + o];
        __syncthreads();
    }
    if (threadIdx.x == 0) bs[blockIdx.x] = s[0];
}

__global__ void ks2(int* __restrict__ bs) {
    __shared__ int s[256];
    int t = threadIdx.x;
    int v[VPT];
    int base = t * VPT, sum = 0;
#pragma unroll
    for (int k = 0; k < VPT; k++) {
        int idx = base + k;
        int x = (idx < NS1) ? bs[idx] : 0;
        v[k] = sum; sum += x;
    }
    s[t] = sum;
    __syncthreads();
    for (int o = 1; o < 256; o <<= 1) {
        int add = (t >= o) ? s[t - o] : 0;
        __syncthreads();
        s[t] += add;
        __syncthreads();
    }
    int excl = (t == 0) ? 0 : s[t - 1];
#pragma unroll
    for (int k = 0; k < VPT; k++) {
        int idx = base + k;
        if (idx < NS1) bs[idx] = excl + v[k];
    }
}

__global__ void ks3(int* __restrict__ a, const int* __restrict__ bs) {
    __shared__ int s[256];
    int t = threadIdx.x, i = blockIdx.x * 256 + t;
    int v = a[i];
    s[t] = v;
    __syncthreads();
    for (int o = 1; o < 256; o <<= 1) {
        int add = (t >= o) ? s[t - o] : 0;
        __syncthreads();
        s[t] += add;
        __syncthreads();
    }
    a[i] = s[t] - v + bs[blockIdx.x];
}

// ---------- phase B: scatter records into 196-bucket-grouped buf1 ----------
__global__ void __launch_bounds__(256) ksB(const int* __restrict__ ei, const float* __restrict__ ea,
                                           const int* __restrict__ cmat, float4* __restrict__ buf1) {
    __shared__ int base[NBKT];
    if (threadIdx.x < NBKT) base[threadIdx.x] = cmat[threadIdx.x * NBLKA + blockIdx.x];
    __syncthreads();
    int b0 = blockIdx.x * CHUNK;
    for (int i = threadIdx.x; i < CHUNK; i += 256) {
        int e = b0 + i;
        if (e >= N_EDGES) break;
        int src = ei[e], dst = ei[N_EDGES + e];
        float a0 = ea[(size_t)e * 3 + 0], a1 = ea[(size_t)e * 3 + 1], a2 = ea[(size_t)e * 3 + 2];
        int pos = atomicAdd(&base[dst >> 9], 1);
        buf1[pos] = make_float4(a0, a1, a2, __int_as_float(src | ((dst & 511) << 17)));
    }
}

// ---------- phase C: per-512-node-bucket exact CSR (1024-thread blocks) ----------
__global__ void __launch_bounds__(1024) ksC(const int* __restrict__ cmat, const float4* __restrict__ buf1,
                                            float4* __restrict__ packed, int* __restrict__ offs) {
    __shared__ int cnt[512];
    __shared__ int sc[512];
    __shared__ int excl[513];
    int g = blockIdx.x, t = threadIdx.x;
    int bb = cmat[g * NBLKA];
    int be = (g == NBKT - 1) ? N_EDGES : cmat[(g + 1) * NBLKA];
    if (t < 512) cnt[t] = 0;
    __syncthreads();
    for (int j = bb + t; j < be; j += 1024) {
        int bits = __float_as_int(buf1[j].w);
        atomicAdd(&cnt[bits >> 17], 1);
    }
    __syncthreads();
    if (t < 512) sc[t] = cnt[t];
    __syncthreads();
    for (int o = 1; o < 512; o <<= 1) {
        int add = 0;
        if (t < 512 && t >= o) add = sc[t - o];
        __syncthreads();
        if (t < 512) sc[t] += add;
        __syncthreads();
    }
    if (t < 512) excl[t] = sc[t] - cnt[t];
    if (t == 511) excl[512] = sc[511];
    __syncthreads();
    if (t < 512) offs[g * 512 + t] = bb + excl[t];
    if (g == NBKT - 1 && t == 0) offs[NPAD2] = N_EDGES;
    if (t < 512) cnt[t] = 0;
    __syncthreads();
    for (int j = bb + t; j < be; j += 1024) {
        float4 r = buf1[j];
        int bits = __float_as_int(r.w);
        int dl = bits >> 17, src = bits & 0x1FFFF;
        int rank = atomicAdd(&cnt[dl], 1);
        packed[bb + excl[dl] + rank] = make_float4(r.x, r.y, r.z, __int_as_float(src));
    }
}

// ---------- pull aggregation: 32 threads/node, 2-way unrolled (dual chains) ----------
__global__ void __launch_bounds__(256) k_agg(const float4* __restrict__ packed,
                                             const int* __restrict__ offs,
                                             const float* __restrict__ eW, const float* __restrict__ eb,
                                             const float* __restrict__ h, float* __restrict__ agg) {
    int t = blockIdx.x * 256 + threadIdx.x;   // N_NODES*32 exact
    int n = t >> 5, s = t & 31;
    int q = s & 7, part = s >> 3;             // quad 0..7, edge-part 0..3
    int c0 = q * 4;
    float w0[4], w1[4], w2[4], bb4[4];
#pragma unroll
    for (int i = 0; i < 4; i++) {
        w0[i] = eW[c0 + i];
        w1[i] = eW[32 + c0 + i];
        w2[i] = eW[64 + c0 + i];
        bb4[i] = eb[c0 + i];
    }
    int beg = offs[n], end = offs[n + 1];
    float acc0[4] = {0.f, 0.f, 0.f, 0.f};
    float acc1[4] = {0.f, 0.f, 0.f, 0.f};
    int j = beg + part;
    for (; j + 4 < end; j += 8) {
        float4 pa = packed[j];
        float4 pb = packed[j + 4];
        int sa = __float_as_int(pa.w);
        int sb = __float_as_int(pb.w);
        float4 ha = *(const float4*)(h + (size_t)sa * 32 + c0);
        float4 hb = *(const float4*)(h + (size_t)sb * 32 + c0);
        const float* hap = (const float*)&ha;
        const float* hbp = (const float*)&hb;
#pragma unroll
        for (int i = 0; i < 4; i++) {
            float ma = hap[i] + pa.x * w0[i] + pa.y * w1[i] + pa.z * w2[i] + bb4[i];
            float mb = hbp[i] + pb.x * w0[i] + pb.y * w1[i] + pb.z * w2[i] + bb4[i];
            acc0[i] += fmaxf(ma, 0.f);
            acc1[i] += fmaxf(mb, 0.f);
        }
    }
    if (j < end) {
        float4 p = packed[j];
        int src = __float_as_int(p.w);
        float4 hs = *(const float4*)(h + (size_t)src * 32 + c0);
        const float* hp = (const float*)&hs;
#pragma unroll
        for (int i = 0; i < 4; i++) {
            float m = hp[i] + p.x * w0[i] + p.y * w1[i] + p.z * w2[i] + bb4[i];
            acc0[i] += fmaxf(m, 0.f);
        }
    }
    float acc[4];
#pragma unroll
    for (int i = 0; i < 4; i++) {
        acc[i] = acc0[i] + acc1[i];
        acc[i] += __shfl_xor(acc[i], 8, 64);
        acc[i] += __shfl_xor(acc[i], 16, 64);
    }
    if (part == 0)
        *(float4*)(agg + (size_t)n * 32 + c0) = make_float4(acc[0], acc[1], acc[2], acc[3]);
}

// ---------- fused MLP: z = relu((h+agg)@W1+b1)@W2+b2, written over agg ----------
// Stage-2 hid exchange through LDS (in-wave producer/consumer, no barrier):
// each lane writes its 10 hid values to hidL[row][oct*10..], reads its node's
// 80-value row back as 20 ds_read_b128 (8-way broadcast, conflict-free).
__global__ void __launch_bounds__(256, 4) k_mlp(const float* __restrict__ h, float* __restrict__ agg,
                                                const float* __restrict__ W1, const float* __restrict__ B1,
                                                const float* __restrict__ W2, const float* __restrict__ b2) {
    __shared__ float hidL[32 * 84];    // 4 waves * 8 nodes; stride 84 (16B-aligned rows, spread banks)
    unsigned t = blockIdx.x * 256 + threadIdx.x;   // N_NODES*8 exact
    unsigned lane = threadIdx.x & 63;
    unsigned wv = threadIdx.x >> 6;
    unsigned oct = lane >> 3;          // hidden-slice / output-quad index
    unsigned nd = lane & 7;            // node within this wave's 8-node group
    unsigned n = (t >> 6) * 8 + nd;    // 12500 waves * 8 nodes = N_NODES exact
    const float4* hp = (const float4*)(h + (size_t)n * 32);
    const float4* ap = (const float4*)(agg + (size_t)n * 32);
    float zc[32];
#pragma unroll
    for (int q = 0; q < 8; q++) {
        float4 hv = hp[q], av = ap[q];
        zc[q * 4 + 0] = hv.x + av.x;
        zc[q * 4 + 1] = hv.y + av.y;
        zc[q * 4 + 2] = hv.z + av.z;
        zc[q * 4 + 3] = hv.w + av.w;
    }
    // stage 1: 10 hidden units per lane (weight rows shared by 8 lanes -> L1 broadcast)
    float hid[10];
#pragma unroll
    for (int i = 0; i < 10; i++) {
        int j = (int)oct * 10 + i;
        const float4* wp = (const float4*)(W1 + j * 32);
        float a0 = 0.f, a1 = 0.f, a2 = 0.f, a3 = 0.f;
#pragma unroll
        for (int q = 0; q < 8; q++) {
            float4 wv4 = wp[q];
            a0 += zc[q * 4 + 0] * wv4.x;
            a1 += zc[q * 4 + 1] * wv4.y;
            a2 += zc[q * 4 + 2] * wv4.z;
            a3 += zc[q * 4 + 3] * wv4.w;
        }
        hid[i] = fmaxf(B1[j] + ((a0 + a1) + (a2 + a3)), 0.f);
    }
    // stage hid through LDS (same-wave lockstep: no __syncthreads needed)
    float* hrow = &hidL[(wv * 8 + nd) * 84];
#pragma unroll
    for (int i = 0; i < 10; i++) hrow[oct * 10 + i] = hid[i];
    // stage 2: own output quad; hid row via b128 LDS reads
    float4 zo = *(const float4*)(b2 + oct * 4);
    const float4* hv4 = (const float4*)hrow;
#pragma unroll
    for (int k = 0; k < 20; k++) {
        float4 hv = hv4[k];
        const float* wr = W2 + (k * 4) * 32 + oct * 4;
        float4 wa = *(const float4*)(wr);
        float4 wb = *(const float4*)(wr + 32);
        float4 wc = *(const float4*)(wr + 64);
        float4 wd = *(const float4*)(wr + 96);
        zo.x += hv.x * wa.x + hv.y * wb.x + hv.z * wc.x + hv.w * wd.x;
        zo.y += hv.x * wa.y + hv.y * wb.y + hv.z * wc.y + hv.w * wd.y;
        zo.z += hv.x * wa.z + hv.y * wb.z + hv.z * wc.z + hv.w * wd.z;
        zo.w += hv.x * wa.w + hv.y * wb.w + hv.z * wc.w + hv.w * wd.w;
    }
    *(float4*)(agg + (size_t)n * 32 + oct * 4) = zo;
}

// ---------- BN stats (separate pass) ----------
__global__ void __launch_bounds__(256) k_stats(const float* __restrict__ z, float* __restrict__ stats) {
    __shared__ float ls[4 * 64];
    int tid = threadIdx.x;
    int c = tid & 31;
    float s = 0.f, s2 = 0.f;
    for (int e = blockIdx.x * 256 + tid; e < N_NODES * 32; e += 256 * 256) {
        float v = z[e];
        s += v; s2 += v * v;
    }
    s += __shfl_down(s, 32, 64);
    s2 += __shfl_down(s2, 32, 64);
    int wave = tid >> 6, lane = tid & 63;
    if (lane < 32) { ls[wave * 64 + c] = s; ls[wave * 64 + 32 + c] = s2; }
    __syncthreads();
    if (tid < 64) {
        float a = ls[tid] + ls[64 + tid] + ls[128 + tid] + ls[192 + tid];
        atomicAdd(&stats[tid], a);
    }
}

// ---------- BN apply + relu ----------
__global__ void k_bn(const float* __restrict__ z, float* __restrict__ h,
                     const float* __restrict__ stats, const float* __restrict__ g,
                     const float* __restrict__ b) {
    int t = blockIdx.x * 256 + threadIdx.x;
    if (t >= N_NODES * 8) return;
    int q = t & 7;
    float4 zv = ((const float4*)z)[t];
    float* zp = (float*)&zv;
    float4 ov;
    float* op = (float*)&ov;
    const float invN = 1.0f / (float)N_NODES;
#pragma unroll
    for (int i = 0; i < 4; i++) {
        int c = q * 4 + i;
        float mu = stats[c] * invN;
        float var = stats[32 + c] * invN - mu * mu;
        float sc = g[c] / sqrtf(var + BN_EPS);
        op[i] = fmaxf((zp[i] - mu) * sc + b[c], 0.f);
    }
    ((float4*)h)[t] = ov;
}

// ---------- graph offsets (batch is sorted) ----------
__global__ void k_goff(const int* __restrict__ batch, int* __restrict__ goff) {
    int g = blockIdx.x * 256 + threadIdx.x;
    if (g > N_GRAPHS) return;
    int lo = 0, hi = N_NODES;
    while (lo < hi) {
        int mid = (lo + hi) >> 1;
        if (batch[mid] < g) lo = mid + 1; else hi = mid;
    }
    goff[g] = lo;
}

// ---------- mean-pool: one wave per graph ----------
__global__ void __launch_bounds__(256) k_pool2(const float* __restrict__ h, const int* __restrict__ goff,
                                               float* __restrict__ gsum) {
    int wid = threadIdx.x >> 6, lane = threadIdx.x & 63;
    int g = blockIdx.x * 4 + wid;
    if (g >= N_GRAPHS) return;
    int s = goff[g], e = goff[g + 1];
    int c = lane & 31, half = lane >> 5;
    float acc = 0.f;
    for (int n = s + half; n < e; n += 2) acc += h[(size_t)n * 32 + c];
    acc += __shfl_down(acc, 32, 64);
    if (lane < 32) gsum[(size_t)g * 32 + c] = acc;
}

__global__ void k_head(const float* __restrict__ gsum, const int* __restrict__ goff,
                       const float* __restrict__ W1, const float* __restrict__ b1,
                       const float* __restrict__ W2, const float* __restrict__ b2,
                       float* __restrict__ out) {
    __shared__ float sW1[512], sb1[16], sW2[32], sb2[2];
    for (int i = threadIdx.x; i < 512; i += 256) sW1[i] = W1[i];
    if (threadIdx.x < 16) sb1[threadIdx.x] = b1[threadIdx.x];
    if (threadIdx.x < 32) sW2[threadIdx.x] = W2[threadIdx.x];
    if (threadIdx.x < 2) sb2[threadIdx.x] = b2[threadIdx.x];
    __syncthreads();
    int gI = blockIdx.x * 256 + threadIdx.x;
    if (gI >= N_GRAPHS) return;
    float cnt = (float)(goff[gI + 1] - goff[gI]);
    float inv = 1.0f / fmaxf(cnt, 1.0f);
    float gx[32];
#pragma unroll
    for (int c = 0; c < 32; c++) gx[c] = gsum[(size_t)gI * 32 + c] * inv;
    float hid[16];
#pragma unroll
    for (int j = 0; j < 16; j++) {
        float a = sb1[j];
#pragma unroll
        for (int c = 0; c < 32; c++) a += gx[c] * sW1[c * 16 + j];
        hid[j] = fmaxf(a, 0.f);
    }
#pragma unroll
    for (int o = 0; o < 2; o++) {
        float a = sb2[o];
#pragma unroll
        for (int j = 0; j < 16; j++) a += hid[j] * sW2[j * 2 + o];
        out[(size_t)gI * 2 + o] = a;
    }
}

extern "C" void kernel_launch(void* const* d_in, const int* in_sizes, int n_in,
                              void* d_out, int out_size, void* d_ws, size_t ws_size,
                              hipStream_t stream) {
    const float* x       = (const float*)d_in[0];
    const int*   ei      = (const int*)d_in[1];
    const float* eattr   = (const float*)d_in[2];
    const int*   batch   = (const int*)d_in[3];
    const float* node_w  = (const float*)d_in[4];
    const float* node_b  = (const float*)d_in[5];
    const float* edge_w  = (const float*)d_in[6];
    const float* edge_b  = (const float*)d_in[7];
    const float* conv_w1 = (const float*)d_in[8];
    const float* conv_b1 = (const float*)d_in[9];
    const float* conv_w2 = (const float*)d_in[10];
    const float* conv_b2 = (const float*)d_in[11];
    const float* bn_g    = (const float*)d_in[12];
    const float* bn_b    = (const float*)d_in[13];
    const float* lin1_w  = (const float*)d_in[14];
    const float* lin1_b  = (const float*)d_in[15];
    const float* lin2_w  = (const float*)d_in[16];
    const float* lin2_b  = (const float*)d_in[17];
    float* out = (float*)d_out;

    float4* packed = (float4*)d_ws;                        // 51.2 MB
    float4* buf1   = packed + N_EDGES;                     // 51.2 MB (CSR build only)
    float*  h      = (float*)(buf1 + N_EDGES);             // 12.8 MB
    float*  agg    = h + (size_t)N_NODES * 32;             // 12.8 MB (z in-place)
    int*    cmat   = (int*)(agg + (size_t)N_NODES * 32);   // LALLOC ints
    int*    t1     = cmat + LALLOC;                        // 768
    int*    offs   = t1 + 768;                             // NPAD2+1
    int*    goff   = offs + NPAD2 + 1;                     // N_GRAPHS+1
    float*  stats  = (float*)(goff + N_GRAPHS + 1);        // 64
    float*  gsum   = stats + 64;                           // G*32
    float*  w1tp   = gsum + (size_t)N_GRAPHS * 32;         // 2*80*32
    float*  b1p    = w1tp + 2 * HPAD * 32;                 // 2*80
    float*  w2p    = b1p + 2 * HPAD;                       // 2*80*32

    int nb_nodes = (N_NODES + 255) / 256;
    int nb_vec   = (N_NODES * 8 + 255) / 256;

    hipMemsetAsync(cmat, 0, LALLOC * sizeof(int), stream);
    k_encode<<<nb_nodes, 256, 0, stream>>>(x, node_w, node_b, h);
    k_prep<<<(2 * HPAD * 32 + 2 * HPAD + 255) / 256, 256, 0, stream>>>(
        conv_w1, conv_b1, conv_w2, w1tp, b1p, w2p);
    k_goff<<<(N_GRAPHS + 1 + 255) / 256, 256, 0, stream>>>(batch, goff);

    ksA<<<NBLKA, 256, 0, stream>>>(ei, cmat);
    ks1<<<NS1, 256, 0, stream>>>(cmat, t1);
    ks2<<<1, 256, 0, stream>>>(t1);
    ks3<<<NS1, 256, 0, stream>>>(cmat, t1);
    ksB<<<NBLKA, 256, 0, stream>>>(ei, eattr, cmat, buf1);
    ksC<<<NBKT, 1024, 0, stream>>>(cmat, buf1, packed, offs);

    for (int l = 0; l < 2; l++) {
        hipMemsetAsync(stats, 0, 64 * sizeof(float), stream);
        k_agg<<<N_NODES * 32 / 256, 256, 0, stream>>>(packed, offs, edge_w, edge_b, h, agg);
        k_mlp<<<N_NODES * 8 / 256, 256, 0, stream>>>(h, agg, w1tp + l * HPAD * 32,
                                                     b1p + l * HPAD, w2p + l * HPAD * 32,
                                                     conv_b2 + l * 32);
        k_stats<<<256, 256, 0, stream>>>(agg, stats);
        k_bn<<<nb_vec, 256, 0, stream>>>(agg, h, stats, bn_g + l * 32, bn_b + l * 32);
    }
    k_pool2<<<(N_GRAPHS + 3) / 4, 256, 0, stream>>>(h, goff, gsum);
    k_head<<<(N_GRAPHS + 255) / 256, 256, 0, stream>>>(gsum, goff, lin1_w, lin1_b, lin2_w, lin2_b, out);
}